// Round 4
// baseline (409.835 us; speedup 1.0000x reference)
//
#include <hip/hip_runtime.h>
#include <cstdint>

// DisjointSet densify + gather, fused, MLP-oriented.
// father[i] <= i (int32 from harness, 64 MB, L3-resident).
// Key change vs prev round: 8 chains per thread advanced in LOCKSTEP so up to
// 8 independent chase loads are in flight per lane (prev: 4 sequential while
// loops -> 1 outstanding dependent load). Chase is latency-bound, not BW-bound
// (VALUBusy 1.5%, hbm 45% of peak last round).

typedef float f32x4 __attribute__((ext_vector_type(4)));

constexpr int EPT = 8;  // elements per thread

__global__ __launch_bounds__(256) void ds_densify_gather(
    const int* __restrict__ father,
    const float* __restrict__ values,
    float* __restrict__ out_root,   // d_out[0 .. n)
    float* __restrict__ out_val,    // d_out[n .. 2n)
    int n)
{
    int base = (blockIdx.x * blockDim.x + threadIdx.x) * EPT;
    if (base >= n) return;

    // Coalesced 32B load of eight int32 parents.
    int4 a = *reinterpret_cast<const int4*>(father + base);
    int4 b = *reinterpret_cast<const int4*>(father + base + 4);
    int p[EPT] = { a.x, a.y, a.z, a.w, b.x, b.y, b.z, b.w };

    bool done[EPT];
    bool anyActive = false;
    #pragma unroll
    for (int j = 0; j < EPT; ++j) {
        done[j] = (p[j] == base + j);   // self-root: no load needed at all
        anyActive |= !done[j];
    }

    // Lockstep chase: each iteration issues up to 8 INDEPENDENT loads before
    // any of them is consumed -> memory-level parallelism across chains.
    while (anyActive) {
        int g[EPT];
        #pragma unroll
        for (int j = 0; j < EPT; ++j)
            if (!done[j]) g[j] = father[p[j]];
        anyActive = false;
        #pragma unroll
        for (int j = 0; j < EPT; ++j) {
            if (!done[j]) {
                done[j] = (g[j] == p[j]);
                p[j] = g[j];
                anyActive |= !done[j];
            }
        }
    }

    // Gather values at roots: 8 independent loads, issued back-to-back.
    float v[EPT], r[EPT];
    #pragma unroll
    for (int j = 0; j < EPT; ++j) v[j] = values[p[j]];
    #pragma unroll
    for (int j = 0; j < EPT; ++j) r[j] = (float)p[j];

    // Streamed outputs: nontemporal, don't evict the L3-resident tables.
    f32x4 r0 = { r[0], r[1], r[2], r[3] };
    f32x4 r1 = { r[4], r[5], r[6], r[7] };
    f32x4 v0 = { v[0], v[1], v[2], v[3] };
    f32x4 v1 = { v[4], v[5], v[6], v[7] };
    __builtin_nontemporal_store(r0, reinterpret_cast<f32x4*>(out_root + base));
    __builtin_nontemporal_store(r1, reinterpret_cast<f32x4*>(out_root + base + 4));
    __builtin_nontemporal_store(v0, reinterpret_cast<f32x4*>(out_val + base));
    __builtin_nontemporal_store(v1, reinterpret_cast<f32x4*>(out_val + base + 4));
}

extern "C" void kernel_launch(void* const* d_in, const int* in_sizes, int n_in,
                              void* d_out, int out_size, void* d_ws, size_t ws_size,
                              hipStream_t stream) {
    const int*   father = (const int*)d_in[0];
    const float* values = (const float*)d_in[1];
    int n = in_sizes[0];                 // 16,777,216
    float* out_root = (float*)d_out;     // f_conv as float32 (exact: ids < 2^24)
    float* out_val  = (float*)d_out + n; // gathered values

    int threads = 256;
    int elems_per_block = threads * EPT;
    int blocks = (n + elems_per_block - 1) / elems_per_block;
    ds_densify_gather<<<blocks, threads, 0, stream>>>(
        father, values, out_root, out_val, n);
}

// Round 5
// 387.669 us; speedup vs baseline: 1.0572x; 1.0572x over previous
//
#include <hip/hip_runtime.h>
#include <cstdint>

// DisjointSet densify + gather, SPLIT into two kernels to keep each
// dispatch's L3 working set under the 256 MB Infinity Cache.
// R4 evidence: fused kernel's footprint (64 father + 64 values + 128 out)
// = 256 MB -> L3 thrash -> FETCH 1.26 GB (matches a "no L3" fetch model),
// random loads served from HBM at 45% peak. Split footprints: 128/192 MB.

typedef float f32x4 __attribute__((ext_vector_type(4)));

constexpr int EPT = 4;  // elements per thread

// K1: chase each node to its root; write root ids as float (exact, <2^24).
// father is both the sequential stream and the random chase table -> let the
// sequential read warm the caches; only the out_root stream is nontemporal.
__global__ __launch_bounds__(256) void ds_densify(
    const int* __restrict__ father,
    float* __restrict__ out_root,
    int n)
{
    int base = (blockIdx.x * blockDim.x + threadIdx.x) * EPT;
    if (base >= n) return;

    int4 f4 = *reinterpret_cast<const int4*>(father + base);
    int p[EPT] = { f4.x, f4.y, f4.z, f4.w };

    #pragma unroll
    for (int j = 0; j < EPT; ++j) {
        int pj = p[j];
        int g = father[pj];
        while (g != pj) { pj = g; g = father[pj]; }
        p[j] = pj;
    }

    f32x4 r = { (float)p[0], (float)p[1], (float)p[2], (float)p[3] };
    __builtin_nontemporal_store(r, reinterpret_cast<f32x4*>(out_root + base));
}

// K2: gather values at roots. roots stream is read once -> nontemporal load
// so it doesn't evict the values table; output stream nontemporal store.
__global__ __launch_bounds__(256) void ds_gather(
    const float* __restrict__ roots,
    const float* __restrict__ values,
    float* __restrict__ out_val,
    int n)
{
    int base = (blockIdx.x * blockDim.x + threadIdx.x) * EPT;
    if (base >= n) return;

    f32x4 r = __builtin_nontemporal_load(
        reinterpret_cast<const f32x4*>(roots + base));
    f32x4 v = { values[(int)r.x], values[(int)r.y],
                values[(int)r.z], values[(int)r.w] };
    __builtin_nontemporal_store(v, reinterpret_cast<f32x4*>(out_val + base));
}

extern "C" void kernel_launch(void* const* d_in, const int* in_sizes, int n_in,
                              void* d_out, int out_size, void* d_ws, size_t ws_size,
                              hipStream_t stream) {
    const int*   father = (const int*)d_in[0];
    const float* values = (const float*)d_in[1];
    int n = in_sizes[0];                 // 16,777,216
    float* out_root = (float*)d_out;     // f_conv as float32 (exact: ids < 2^24)
    float* out_val  = (float*)d_out + n; // gathered values

    int threads = 256;
    int elems_per_block = threads * EPT;
    int blocks = (n + elems_per_block - 1) / elems_per_block;

    ds_densify<<<blocks, threads, 0, stream>>>(father, out_root, n);
    ds_gather<<<blocks, threads, 0, stream>>>(out_root, values, out_val, n);
}

// Round 6
// 376.852 us; speedup vs baseline: 1.0875x; 1.0287x over previous
//
#include <hip/hip_runtime.h>
#include <cstdint>

// DisjointSet densify + gather, split kernels.
// R5 finding: dur = TCC_bytes / 3.63 TB/s exactly, across every structure
// tried -> byte-bound at a fixed random-line service rate. This round cuts
// bytes by keeping STREAMS out of L2 (nontemporal) so the 4 MB/XCD L2s
// retain the hot chase/gather lines (hop targets are ln(1/x)-weighted toward
// the low-index prefix; values reuse is ~32 uses/line if retained).

typedef float f32x4 __attribute__((ext_vector_type(4)));
typedef int   i32x4 __attribute__((ext_vector_type(4)));

constexpr int EPT = 4;  // elements per thread

// K1: chase each node to its root; write root ids as float (exact, <2^24).
// Stream reads/writes NT; chase loads cached (they own L2 now).
__global__ __launch_bounds__(256) void ds_densify(
    const int* __restrict__ father,
    float* __restrict__ out_root,
    int n)
{
    int base = (blockIdx.x * blockDim.x + threadIdx.x) * EPT;
    if (base >= n) return;

    i32x4 f4 = __builtin_nontemporal_load(
        reinterpret_cast<const i32x4*>(father + base));
    int p[EPT] = { f4.x, f4.y, f4.z, f4.w };

    #pragma unroll
    for (int j = 0; j < EPT; ++j) {
        int pj = p[j];
        if (pj != base + j) {            // self-roots: zero chase loads
            int g = father[pj];
            while (g != pj) { pj = g; g = father[pj]; }
            p[j] = pj;
        }
    }

    f32x4 r = { (float)p[0], (float)p[1], (float)p[2], (float)p[3] };
    __builtin_nontemporal_store(r, reinterpret_cast<f32x4*>(out_root + base));
}

// K2: gather values at roots. roots stream NT-in, values cached, output NT.
__global__ __launch_bounds__(256) void ds_gather(
    const float* __restrict__ roots,
    const float* __restrict__ values,
    float* __restrict__ out_val,
    int n)
{
    int base = (blockIdx.x * blockDim.x + threadIdx.x) * EPT;
    if (base >= n) return;

    f32x4 r = __builtin_nontemporal_load(
        reinterpret_cast<const f32x4*>(roots + base));
    f32x4 v = { values[(int)r.x], values[(int)r.y],
                values[(int)r.z], values[(int)r.w] };
    __builtin_nontemporal_store(v, reinterpret_cast<f32x4*>(out_val + base));
}

extern "C" void kernel_launch(void* const* d_in, const int* in_sizes, int n_in,
                              void* d_out, int out_size, void* d_ws, size_t ws_size,
                              hipStream_t stream) {
    const int*   father = (const int*)d_in[0];
    const float* values = (const float*)d_in[1];
    int n = in_sizes[0];                 // 16,777,216
    float* out_root = (float*)d_out;     // f_conv as float32 (exact: ids < 2^24)
    float* out_val  = (float*)d_out + n; // gathered values

    int threads = 256;
    int elems_per_block = threads * EPT;
    int blocks = (n + elems_per_block - 1) / elems_per_block;

    ds_densify<<<blocks, threads, 0, stream>>>(father, out_root, n);
    ds_gather<<<blocks, threads, 0, stream>>>(out_root, values, out_val, n);
}